// Round 2
// baseline (147.399 us; speedup 1.0000x reference)
//
#include <hip/hip_runtime.h>

#define DIM 1024
#define RPW 4        // rows per wave
#define WAVES 4      // waves per block
#define ROWS_PER_BLOCK (RPW * WAVES)
#define PACKED_BYTES (6 * 4 * 64 * 8 * 4)   // stages 2..7, 4 q, 64 lanes, 8 floats

// Butterfly mixer: 10 stages, stage i mixes (j, j+2^i) with Ws[i][p], p = j with bit i removed.
// Element j = q*256 + lane*4 + c  (q,c in [0,4), lane in [0,64)) lives in d[r][q*4+c].
// -> bits {0,1} = c, bits {2..7} = lane, bits {8,9} = q.
// Stages 0,1,8,9 are thread-local; stages 2..7 are __shfl_xor with mask 2^(i-2).

// Pre-pack stage 2..7 weights: for each (i,q,lane) the 8 floats that lane actually
// uses (wA[e] = diag coeff, wB[e] = partner coeff, e=0..3), as 2 contiguous float4.
__global__ void pack_weights(const float* __restrict__ Ws, float* __restrict__ pw) {
    int t = blockIdx.x * blockDim.x + threadIdx.x; // 0..1535
    if (t >= 6 * 4 * 64) return;
    int lane = t & 63;
    int q = (t >> 6) & 3;
    int i = (t >> 8) + 2;          // 2..7
    int m = 1 << (i - 2);
    int a = (lane >> (i - 2)) & 1;
    int P0 = (((q * 64 + lane) >> (i - 1)) << i) | ((lane & (m - 1)) << 2);
    const float4* Wm = (const float4*)Ws;
    float4 wa, wb;
    float* pa = (float*)&wa;
    float* pb = (float*)&wb;
    #pragma unroll
    for (int e = 0; e < 4; ++e) {
        float4 M = Wm[i * 512 + P0 + e];
        pa[e] = a ? M.w : M.x;     // coeff multiplying my own value
        pb[e] = a ? M.y : M.z;     // coeff multiplying partner's value
    }
    float4* o = (float4*)pw + (size_t)t * 2;
    o[0] = wa;
    o[1] = wb;
}

template <bool PACKED, int MINB>
__global__ __launch_bounds__(256, MINB) void butterfly_kernel(
    const float* __restrict__ x,
    const float* __restrict__ Ws,
    const float* __restrict__ pw,
    float* __restrict__ out,
    int rows)
{
    const int lane = threadIdx.x & 63;
    const int wave = threadIdx.x >> 6;
    const int row0 = (blockIdx.x * WAVES + wave) * RPW;

    const float4* __restrict__ Wm = (const float4*)Ws;

    float d[RPW][16];

    // ---- load: coalesced float4 ----
    #pragma unroll
    for (int r = 0; r < RPW; ++r) {
        int row = row0 + r;
        if (row < rows) {
            const float4* src = (const float4*)(x + (size_t)row * DIM);
            #pragma unroll
            for (int q = 0; q < 4; ++q) {
                float4 v = src[q * 64 + lane];
                d[r][q*4+0] = v.x; d[r][q*4+1] = v.y;
                d[r][q*4+2] = v.z; d[r][q*4+3] = v.w;
            }
        } else {
            #pragma unroll
            for (int e = 0; e < 16; ++e) d[r][e] = 0.f;
        }
    }

    // ---- stage 0: pairs (c,c+1); p = q*128 + lane*2 + (c>>1) ----
    #pragma unroll
    for (int q = 0; q < 4; ++q) {
        int base = 0*512 + q*128 + lane*2;
        float4 m0 = Wm[base], m1 = Wm[base+1];
        #pragma unroll
        for (int r = 0; r < RPW; ++r) {
            int e = q*4;
            float u = d[r][e+0], v = d[r][e+1];
            d[r][e+0] = u*m0.x + v*m0.z;
            d[r][e+1] = u*m0.y + v*m0.w;
            u = d[r][e+2]; v = d[r][e+3];
            d[r][e+2] = u*m1.x + v*m1.z;
            d[r][e+3] = u*m1.y + v*m1.w;
        }
    }

    // ---- stage 1: pairs (c,c+2); p = q*128 + lane*2 + (c&1) ----
    #pragma unroll
    for (int q = 0; q < 4; ++q) {
        int base = 1*512 + q*128 + lane*2;
        float4 m0 = Wm[base], m1 = Wm[base+1];
        #pragma unroll
        for (int r = 0; r < RPW; ++r) {
            int e = q*4;
            float u = d[r][e+0], v = d[r][e+2];
            d[r][e+0] = u*m0.x + v*m0.z;
            d[r][e+2] = u*m0.y + v*m0.w;
            u = d[r][e+1]; v = d[r][e+3];
            d[r][e+1] = u*m1.x + v*m1.z;
            d[r][e+3] = u*m1.y + v*m1.w;
        }
    }

    // ---- stages 2..7: cross-lane, mask m = 2^(i-2) ----
    #pragma unroll
    for (int i = 2; i < 8; ++i) {
        const int m = 1 << (i - 2);
        #pragma unroll
        for (int q = 0; q < 4; ++q) {
            float wA0, wA1, wA2, wA3, wB0, wB1, wB2, wB3;
            if (PACKED) {
                const float4* wp = (const float4*)pw
                    + ((size_t)(((i - 2) * 4 + q) * 64 + lane)) * 2;
                float4 wa = wp[0], wb = wp[1];
                wA0 = wa.x; wA1 = wa.y; wA2 = wa.z; wA3 = wa.w;
                wB0 = wb.x; wB1 = wb.y; wB2 = wb.z; wB3 = wb.w;
            } else {
                const int a = (lane >> (i - 2)) & 1;
                int P0 = (((q*64 + lane) >> (i-1)) << i) | ((lane & (m-1)) << 2);
                int base = i*512 + P0;
                float4 M0 = Wm[base+0], M1 = Wm[base+1], M2 = Wm[base+2], M3 = Wm[base+3];
                wA0 = a ? M0.w : M0.x; wB0 = a ? M0.y : M0.z;
                wA1 = a ? M1.w : M1.x; wB1 = a ? M1.y : M1.z;
                wA2 = a ? M2.w : M2.x; wB2 = a ? M2.y : M2.z;
                wA3 = a ? M3.w : M3.x; wB3 = a ? M3.y : M3.z;
            }
            #pragma unroll
            for (int r = 0; r < RPW; ++r) {
                int e = q*4;
                float o0 = __shfl_xor(d[r][e+0], m);
                float o1 = __shfl_xor(d[r][e+1], m);
                float o2 = __shfl_xor(d[r][e+2], m);
                float o3 = __shfl_xor(d[r][e+3], m);
                d[r][e+0] = d[r][e+0]*wA0 + o0*wB0;
                d[r][e+1] = d[r][e+1]*wA1 + o1*wB1;
                d[r][e+2] = d[r][e+2]*wA2 + o2*wB2;
                d[r][e+3] = d[r][e+3]*wA3 + o3*wB3;
            }
        }
    }

    // ---- stage 8: pairs (q, q+1) for q in {0,2}; p = (q>>1)*256 + lane*4 + c ----
    #pragma unroll
    for (int qp = 0; qp < 2; ++qp) {
        int base = 8*512 + qp*256 + lane*4;
        float4 M0 = Wm[base+0], M1 = Wm[base+1], M2 = Wm[base+2], M3 = Wm[base+3];
        #pragma unroll
        for (int r = 0; r < RPW; ++r) {
            int eu = (2*qp)*4, ev = (2*qp+1)*4;
            float u, v;
            u = d[r][eu+0]; v = d[r][ev+0]; d[r][eu+0] = u*M0.x + v*M0.z; d[r][ev+0] = u*M0.y + v*M0.w;
            u = d[r][eu+1]; v = d[r][ev+1]; d[r][eu+1] = u*M1.x + v*M1.z; d[r][ev+1] = u*M1.y + v*M1.w;
            u = d[r][eu+2]; v = d[r][ev+2]; d[r][eu+2] = u*M2.x + v*M2.z; d[r][ev+2] = u*M2.y + v*M2.w;
            u = d[r][eu+3]; v = d[r][ev+3]; d[r][eu+3] = u*M3.x + v*M3.z; d[r][ev+3] = u*M3.y + v*M3.w;
        }
    }

    // ---- stage 9: pairs (q, q+2) for q in {0,1}; p = (q&1)*256 + lane*4 + c ----
    #pragma unroll
    for (int qp = 0; qp < 2; ++qp) {
        int base = 9*512 + qp*256 + lane*4;
        float4 M0 = Wm[base+0], M1 = Wm[base+1], M2 = Wm[base+2], M3 = Wm[base+3];
        #pragma unroll
        for (int r = 0; r < RPW; ++r) {
            int eu = qp*4, ev = (qp+2)*4;
            float u, v;
            u = d[r][eu+0]; v = d[r][ev+0]; d[r][eu+0] = u*M0.x + v*M0.z; d[r][ev+0] = u*M0.y + v*M0.w;
            u = d[r][eu+1]; v = d[r][ev+1]; d[r][eu+1] = u*M1.x + v*M1.z; d[r][ev+1] = u*M1.y + v*M1.w;
            u = d[r][eu+2]; v = d[r][ev+2]; d[r][eu+2] = u*M2.x + v*M2.z; d[r][ev+2] = u*M2.y + v*M2.w;
            u = d[r][eu+3]; v = d[r][ev+3]; d[r][eu+3] = u*M3.x + v*M3.z; d[r][ev+3] = u*M3.y + v*M3.w;
        }
    }

    // ---- store: coalesced float4 ----
    #pragma unroll
    for (int r = 0; r < RPW; ++r) {
        int row = row0 + r;
        if (row < rows) {
            float4* dst = (float4*)(out + (size_t)row * DIM);
            #pragma unroll
            for (int q = 0; q < 4; ++q) {
                float4 v;
                v.x = d[r][q*4+0]; v.y = d[r][q*4+1];
                v.z = d[r][q*4+2]; v.w = d[r][q*4+3];
                dst[q * 64 + lane] = v;
            }
        }
    }
}

extern "C" void kernel_launch(void* const* d_in, const int* in_sizes, int n_in,
                              void* d_out, int out_size, void* d_ws, size_t ws_size,
                              hipStream_t stream) {
    const float* x  = (const float*)d_in[0];
    const float* Ws = (const float*)d_in[1];
    float* out = (float*)d_out;

    int rows = in_sizes[0] / DIM;
    int grid = (rows + ROWS_PER_BLOCK - 1) / ROWS_PER_BLOCK;

    if (ws_size >= (size_t)PACKED_BYTES) {
        float* pw = (float*)d_ws;
        pack_weights<<<6, 256, 0, stream>>>(Ws, pw);
        butterfly_kernel<true, 5><<<grid, 256, 0, stream>>>(x, Ws, pw, out, rows);
    } else {
        butterfly_kernel<false, 4><<<grid, 256, 0, stream>>>(x, Ws, nullptr, out, rows);
    }
}

// Round 4
// 101.038 us; speedup vs baseline: 1.4588x; 1.4588x over previous
//
#include <hip/hip_runtime.h>

#define DIM 1024
#define RPW 4        // rows per wave
#define WAVES 4      // waves per block
#define ROWS_PER_BLOCK (RPW * WAVES)
#define PACKED_BYTES (6 * 4 * 64 * 8 * 4)   // stages 2..7, 4 q, 64 lanes, 8 floats

typedef float f32x4 __attribute__((ext_vector_type(4)));  // native vec for NT builtins

// Butterfly mixer: 10 stages, stage i mixes (j, j+2^i) with Ws[i][p], p = j with bit i removed.
// Element j = q*256 + lane*4 + c  (q,c in [0,4), lane in [0,64)) lives in d[r][q*4+c].
// -> bits {0,1} = c, bits {2..7} = lane, bits {8,9} = q.
// Stages 0,1,8,9 are thread-local; stages 2..7 are __shfl_xor with mask 2^(i-2).

// Pre-pack stage 2..7 weights: for each (i,q,lane) the 8 floats that lane actually
// uses (wA[e] = diag coeff, wB[e] = partner coeff, e=0..3), as 2 contiguous float4.
__global__ void pack_weights(const float* __restrict__ Ws, float* __restrict__ pw) {
    int t = blockIdx.x * blockDim.x + threadIdx.x; // 0..1535
    if (t >= 6 * 4 * 64) return;
    int lane = t & 63;
    int q = (t >> 6) & 3;
    int i = (t >> 8) + 2;          // 2..7
    int m = 1 << (i - 2);
    int a = (lane >> (i - 2)) & 1;
    int P0 = (((q * 64 + lane) >> (i - 1)) << i) | ((lane & (m - 1)) << 2);
    const float4* Wm = (const float4*)Ws;
    float4 wa, wb;
    float* pa = (float*)&wa;
    float* pb = (float*)&wb;
    #pragma unroll
    for (int e = 0; e < 4; ++e) {
        float4 M = Wm[i * 512 + P0 + e];
        pa[e] = a ? M.w : M.x;     // coeff multiplying my own value
        pb[e] = a ? M.y : M.z;     // coeff multiplying partner's value
    }
    float4* o = (float4*)pw + (size_t)t * 2;
    o[0] = wa;
    o[1] = wb;
}

template <bool PACKED>
__global__ __launch_bounds__(256, 4) void butterfly_kernel(
    const float* __restrict__ x,
    const float* __restrict__ Ws,
    const float* __restrict__ pw,
    float* __restrict__ out,
    int rows)
{
    const int lane = threadIdx.x & 63;
    const int wave = threadIdx.x >> 6;
    const int row0 = (blockIdx.x * WAVES + wave) * RPW;

    const float4* __restrict__ Wm = (const float4*)Ws;

    float d[RPW][16];

    // ---- load: coalesced float4, nontemporal (read-once stream; keep L2 for weights) ----
    #pragma unroll
    for (int r = 0; r < RPW; ++r) {
        int row = row0 + r;
        if (row < rows) {
            const f32x4* src = (const f32x4*)(x + (size_t)row * DIM);
            #pragma unroll
            for (int q = 0; q < 4; ++q) {
                f32x4 v = __builtin_nontemporal_load(&src[q * 64 + lane]);
                d[r][q*4+0] = v.x; d[r][q*4+1] = v.y;
                d[r][q*4+2] = v.z; d[r][q*4+3] = v.w;
            }
        } else {
            #pragma unroll
            for (int e = 0; e < 16; ++e) d[r][e] = 0.f;
        }
    }

    // ---- stage 0: pairs (c,c+1); p = q*128 + lane*2 + (c>>1) ----
    #pragma unroll
    for (int q = 0; q < 4; ++q) {
        int base = 0*512 + q*128 + lane*2;
        float4 m0 = Wm[base], m1 = Wm[base+1];
        #pragma unroll
        for (int r = 0; r < RPW; ++r) {
            int e = q*4;
            float u = d[r][e+0], v = d[r][e+1];
            d[r][e+0] = u*m0.x + v*m0.z;
            d[r][e+1] = u*m0.y + v*m0.w;
            u = d[r][e+2]; v = d[r][e+3];
            d[r][e+2] = u*m1.x + v*m1.z;
            d[r][e+3] = u*m1.y + v*m1.w;
        }
    }

    // ---- stage 1: pairs (c,c+2); p = q*128 + lane*2 + (c&1) ----
    #pragma unroll
    for (int q = 0; q < 4; ++q) {
        int base = 1*512 + q*128 + lane*2;
        float4 m0 = Wm[base], m1 = Wm[base+1];
        #pragma unroll
        for (int r = 0; r < RPW; ++r) {
            int e = q*4;
            float u = d[r][e+0], v = d[r][e+2];
            d[r][e+0] = u*m0.x + v*m0.z;
            d[r][e+2] = u*m0.y + v*m0.w;
            u = d[r][e+1]; v = d[r][e+3];
            d[r][e+1] = u*m1.x + v*m1.z;
            d[r][e+3] = u*m1.y + v*m1.w;
        }
    }

    // ---- stages 2..7: cross-lane, mask m = 2^(i-2) ----
    #pragma unroll
    for (int i = 2; i < 8; ++i) {
        const int m = 1 << (i - 2);
        #pragma unroll
        for (int q = 0; q < 4; ++q) {
            float wA0, wA1, wA2, wA3, wB0, wB1, wB2, wB3;
            if (PACKED) {
                const float4* wp = (const float4*)pw
                    + ((size_t)(((i - 2) * 4 + q) * 64 + lane)) * 2;
                float4 wa = wp[0], wb = wp[1];
                wA0 = wa.x; wA1 = wa.y; wA2 = wa.z; wA3 = wa.w;
                wB0 = wb.x; wB1 = wb.y; wB2 = wb.z; wB3 = wb.w;
            } else {
                const int a = (lane >> (i - 2)) & 1;
                int P0 = (((q*64 + lane) >> (i-1)) << i) | ((lane & (m-1)) << 2);
                int base = i*512 + P0;
                float4 M0 = Wm[base+0], M1 = Wm[base+1], M2 = Wm[base+2], M3 = Wm[base+3];
                wA0 = a ? M0.w : M0.x; wB0 = a ? M0.y : M0.z;
                wA1 = a ? M1.w : M1.x; wB1 = a ? M1.y : M1.z;
                wA2 = a ? M2.w : M2.x; wB2 = a ? M2.y : M2.z;
                wA3 = a ? M3.w : M3.x; wB3 = a ? M3.y : M3.z;
            }
            #pragma unroll
            for (int r = 0; r < RPW; ++r) {
                int e = q*4;
                float o0 = __shfl_xor(d[r][e+0], m);
                float o1 = __shfl_xor(d[r][e+1], m);
                float o2 = __shfl_xor(d[r][e+2], m);
                float o3 = __shfl_xor(d[r][e+3], m);
                d[r][e+0] = d[r][e+0]*wA0 + o0*wB0;
                d[r][e+1] = d[r][e+1]*wA1 + o1*wB1;
                d[r][e+2] = d[r][e+2]*wA2 + o2*wB2;
                d[r][e+3] = d[r][e+3]*wA3 + o3*wB3;
            }
        }
    }

    // ---- stage 8: pairs (q, q+1) for q in {0,2}; p = (q>>1)*256 + lane*4 + c ----
    #pragma unroll
    for (int qp = 0; qp < 2; ++qp) {
        int base = 8*512 + qp*256 + lane*4;
        float4 M0 = Wm[base+0], M1 = Wm[base+1], M2 = Wm[base+2], M3 = Wm[base+3];
        #pragma unroll
        for (int r = 0; r < RPW; ++r) {
            int eu = (2*qp)*4, ev = (2*qp+1)*4;
            float u, v;
            u = d[r][eu+0]; v = d[r][ev+0]; d[r][eu+0] = u*M0.x + v*M0.z; d[r][ev+0] = u*M0.y + v*M0.w;
            u = d[r][eu+1]; v = d[r][ev+1]; d[r][eu+1] = u*M1.x + v*M1.z; d[r][ev+1] = u*M1.y + v*M1.w;
            u = d[r][eu+2]; v = d[r][ev+2]; d[r][eu+2] = u*M2.x + v*M2.z; d[r][ev+2] = u*M2.y + v*M2.w;
            u = d[r][eu+3]; v = d[r][ev+3]; d[r][eu+3] = u*M3.x + v*M3.z; d[r][ev+3] = u*M3.y + v*M3.w;
        }
    }

    // ---- stage 9: pairs (q, q+2) for q in {0,1}; p = (q&1)*256 + lane*4 + c ----
    #pragma unroll
    for (int qp = 0; qp < 2; ++qp) {
        int base = 9*512 + qp*256 + lane*4;
        float4 M0 = Wm[base+0], M1 = Wm[base+1], M2 = Wm[base+2], M3 = Wm[base+3];
        #pragma unroll
        for (int r = 0; r < RPW; ++r) {
            int eu = qp*4, ev = (qp+2)*4;
            float u, v;
            u = d[r][eu+0]; v = d[r][ev+0]; d[r][eu+0] = u*M0.x + v*M0.z; d[r][ev+0] = u*M0.y + v*M0.w;
            u = d[r][eu+1]; v = d[r][ev+1]; d[r][eu+1] = u*M1.x + v*M1.z; d[r][ev+1] = u*M1.y + v*M1.w;
            u = d[r][eu+2]; v = d[r][ev+2]; d[r][eu+2] = u*M2.x + v*M2.z; d[r][ev+2] = u*M2.y + v*M2.w;
            u = d[r][eu+3]; v = d[r][ev+3]; d[r][eu+3] = u*M3.x + v*M3.z; d[r][ev+3] = u*M3.y + v*M3.w;
        }
    }

    // ---- store: coalesced float4, nontemporal (write-once stream) ----
    #pragma unroll
    for (int r = 0; r < RPW; ++r) {
        int row = row0 + r;
        if (row < rows) {
            f32x4* dst = (f32x4*)(out + (size_t)row * DIM);
            #pragma unroll
            for (int q = 0; q < 4; ++q) {
                f32x4 v;
                v.x = d[r][q*4+0]; v.y = d[r][q*4+1];
                v.z = d[r][q*4+2]; v.w = d[r][q*4+3];
                __builtin_nontemporal_store(v, &dst[q * 64 + lane]);
            }
        }
    }
}

extern "C" void kernel_launch(void* const* d_in, const int* in_sizes, int n_in,
                              void* d_out, int out_size, void* d_ws, size_t ws_size,
                              hipStream_t stream) {
    const float* x  = (const float*)d_in[0];
    const float* Ws = (const float*)d_in[1];
    float* out = (float*)d_out;

    int rows = in_sizes[0] / DIM;
    int grid = (rows + ROWS_PER_BLOCK - 1) / ROWS_PER_BLOCK;

    if (ws_size >= (size_t)PACKED_BYTES) {
        float* pw = (float*)d_ws;
        pack_weights<<<6, 256, 0, stream>>>(Ws, pw);
        butterfly_kernel<true><<<grid, 256, 0, stream>>>(x, Ws, pw, out, rows);
    } else {
        butterfly_kernel<false><<<grid, 256, 0, stream>>>(x, Ws, nullptr, out, rows);
    }
}

// Round 6
// 47.000 us; speedup vs baseline: 3.1362x; 2.1498x over previous
//
#include <hip/hip_runtime.h>

#define DIM 1024
#define RPW 2        // rows per wave (halved: d[] = 32 VGPRs -> higher occupancy)
#define WAVES 4      // waves per block
#define ROWS_PER_BLOCK (RPW * WAVES)
#define PACKED_BYTES (6 * 4 * 64 * 8 * 4)   // stages 2..7, 4 q, 64 lanes, 8 floats

typedef float f32x4 __attribute__((ext_vector_type(4)));  // native vec for NT builtins

// Butterfly mixer: 10 stages, stage i mixes (j, j+2^i) with Ws[i][p], p = j with bit i removed.
// Element j = q*256 + lane*4 + c  (q,c in [0,4), lane in [0,64)) lives in d[r][q*4+c].
// -> bits {0,1} = c, bits {2..7} = lane, bits {8,9} = q.
// Stages 0,1,8,9 are thread-local; stages 2..7 are __shfl_xor with mask 2^(i-2).
// NOTE: do NOT use the 2nd __launch_bounds__ arg — measured VGPR cap ~256/minwaves
// (r2: w=5 -> 48 VGPR, r4: w=4 -> 64 VGPR), which forces scratch spills (d[] alone
// needs RPW*16 VGPRs). Compiler-chosen allocation (r1: 128 VGPR) has zero spill.

// Pre-pack stage 2..7 weights: for each (i,q,lane) the 8 floats that lane actually
// uses (wA[e] = diag coeff, wB[e] = partner coeff, e=0..3), as 2 contiguous float4.
__global__ void pack_weights(const float* __restrict__ Ws, float* __restrict__ pw) {
    int t = blockIdx.x * blockDim.x + threadIdx.x; // 0..1535
    if (t >= 6 * 4 * 64) return;
    int lane = t & 63;
    int q = (t >> 6) & 3;
    int i = (t >> 8) + 2;          // 2..7
    int m = 1 << (i - 2);
    int a = (lane >> (i - 2)) & 1;
    int P0 = (((q * 64 + lane) >> (i - 1)) << i) | ((lane & (m - 1)) << 2);
    const float4* Wm = (const float4*)Ws;
    float4 wa, wb;
    float* pa = (float*)&wa;
    float* pb = (float*)&wb;
    #pragma unroll
    for (int e = 0; e < 4; ++e) {
        float4 M = Wm[i * 512 + P0 + e];
        pa[e] = a ? M.w : M.x;     // coeff multiplying my own value
        pb[e] = a ? M.y : M.z;     // coeff multiplying partner's value
    }
    float4* o = (float4*)pw + (size_t)t * 2;
    o[0] = wa;
    o[1] = wb;
}

template <bool PACKED>
__global__ __launch_bounds__(256) void butterfly_kernel(
    const float* __restrict__ x,
    const float* __restrict__ Ws,
    const float* __restrict__ pw,
    float* __restrict__ out,
    int rows)
{
    const int lane = threadIdx.x & 63;
    const int wave = threadIdx.x >> 6;
    const int row0 = (blockIdx.x * WAVES + wave) * RPW;

    const float4* __restrict__ Wm = (const float4*)Ws;

    float d[RPW][16];

    // ---- load: coalesced float4, nontemporal (read-once stream; keep L2 for weights) ----
    #pragma unroll
    for (int r = 0; r < RPW; ++r) {
        int row = row0 + r;
        if (row < rows) {
            const f32x4* src = (const f32x4*)(x + (size_t)row * DIM);
            #pragma unroll
            for (int q = 0; q < 4; ++q) {
                f32x4 v = __builtin_nontemporal_load(&src[q * 64 + lane]);
                d[r][q*4+0] = v.x; d[r][q*4+1] = v.y;
                d[r][q*4+2] = v.z; d[r][q*4+3] = v.w;
            }
        } else {
            #pragma unroll
            for (int e = 0; e < 16; ++e) d[r][e] = 0.f;
        }
    }

    // ---- stage 0: pairs (c,c+1); p = q*128 + lane*2 + (c>>1) ----
    #pragma unroll
    for (int q = 0; q < 4; ++q) {
        int base = 0*512 + q*128 + lane*2;
        float4 m0 = Wm[base], m1 = Wm[base+1];
        #pragma unroll
        for (int r = 0; r < RPW; ++r) {
            int e = q*4;
            float u = d[r][e+0], v = d[r][e+1];
            d[r][e+0] = u*m0.x + v*m0.z;
            d[r][e+1] = u*m0.y + v*m0.w;
            u = d[r][e+2]; v = d[r][e+3];
            d[r][e+2] = u*m1.x + v*m1.z;
            d[r][e+3] = u*m1.y + v*m1.w;
        }
    }

    // ---- stage 1: pairs (c,c+2); p = q*128 + lane*2 + (c&1) ----
    #pragma unroll
    for (int q = 0; q < 4; ++q) {
        int base = 1*512 + q*128 + lane*2;
        float4 m0 = Wm[base], m1 = Wm[base+1];
        #pragma unroll
        for (int r = 0; r < RPW; ++r) {
            int e = q*4;
            float u = d[r][e+0], v = d[r][e+2];
            d[r][e+0] = u*m0.x + v*m0.z;
            d[r][e+2] = u*m0.y + v*m0.w;
            u = d[r][e+1]; v = d[r][e+3];
            d[r][e+1] = u*m1.x + v*m1.z;
            d[r][e+3] = u*m1.y + v*m1.w;
        }
    }

    // ---- stages 2..7: cross-lane, mask m = 2^(i-2) ----
    #pragma unroll
    for (int i = 2; i < 8; ++i) {
        const int m = 1 << (i - 2);
        #pragma unroll
        for (int q = 0; q < 4; ++q) {
            float wA0, wA1, wA2, wA3, wB0, wB1, wB2, wB3;
            if (PACKED) {
                const float4* wp = (const float4*)pw
                    + ((size_t)(((i - 2) * 4 + q) * 64 + lane)) * 2;
                float4 wa = wp[0], wb = wp[1];
                wA0 = wa.x; wA1 = wa.y; wA2 = wa.z; wA3 = wa.w;
                wB0 = wb.x; wB1 = wb.y; wB2 = wb.z; wB3 = wb.w;
            } else {
                const int a = (lane >> (i - 2)) & 1;
                int P0 = (((q*64 + lane) >> (i-1)) << i) | ((lane & (m-1)) << 2);
                int base = i*512 + P0;
                float4 M0 = Wm[base+0], M1 = Wm[base+1], M2 = Wm[base+2], M3 = Wm[base+3];
                wA0 = a ? M0.w : M0.x; wB0 = a ? M0.y : M0.z;
                wA1 = a ? M1.w : M1.x; wB1 = a ? M1.y : M1.z;
                wA2 = a ? M2.w : M2.x; wB2 = a ? M2.y : M2.z;
                wA3 = a ? M3.w : M3.x; wB3 = a ? M3.y : M3.z;
            }
            #pragma unroll
            for (int r = 0; r < RPW; ++r) {
                int e = q*4;
                float o0 = __shfl_xor(d[r][e+0], m);
                float o1 = __shfl_xor(d[r][e+1], m);
                float o2 = __shfl_xor(d[r][e+2], m);
                float o3 = __shfl_xor(d[r][e+3], m);
                d[r][e+0] = d[r][e+0]*wA0 + o0*wB0;
                d[r][e+1] = d[r][e+1]*wA1 + o1*wB1;
                d[r][e+2] = d[r][e+2]*wA2 + o2*wB2;
                d[r][e+3] = d[r][e+3]*wA3 + o3*wB3;
            }
        }
    }

    // ---- stage 8: pairs (q, q+1) for q in {0,2}; p = (q>>1)*256 + lane*4 + c ----
    #pragma unroll
    for (int qp = 0; qp < 2; ++qp) {
        int base = 8*512 + qp*256 + lane*4;
        float4 M0 = Wm[base+0], M1 = Wm[base+1], M2 = Wm[base+2], M3 = Wm[base+3];
        #pragma unroll
        for (int r = 0; r < RPW; ++r) {
            int eu = (2*qp)*4, ev = (2*qp+1)*4;
            float u, v;
            u = d[r][eu+0]; v = d[r][ev+0]; d[r][eu+0] = u*M0.x + v*M0.z; d[r][ev+0] = u*M0.y + v*M0.w;
            u = d[r][eu+1]; v = d[r][ev+1]; d[r][eu+1] = u*M1.x + v*M1.z; d[r][ev+1] = u*M1.y + v*M1.w;
            u = d[r][eu+2]; v = d[r][ev+2]; d[r][eu+2] = u*M2.x + v*M2.z; d[r][ev+2] = u*M2.y + v*M2.w;
            u = d[r][eu+3]; v = d[r][ev+3]; d[r][eu+3] = u*M3.x + v*M3.z; d[r][ev+3] = u*M3.y + v*M3.w;
        }
    }

    // ---- stage 9: pairs (q, q+2) for q in {0,1}; p = (q&1)*256 + lane*4 + c ----
    #pragma unroll
    for (int qp = 0; qp < 2; ++qp) {
        int base = 9*512 + qp*256 + lane*4;
        float4 M0 = Wm[base+0], M1 = Wm[base+1], M2 = Wm[base+2], M3 = Wm[base+3];
        #pragma unroll
        for (int r = 0; r < RPW; ++r) {
            int eu = qp*4, ev = (qp+2)*4;
            float u, v;
            u = d[r][eu+0]; v = d[r][ev+0]; d[r][eu+0] = u*M0.x + v*M0.z; d[r][ev+0] = u*M0.y + v*M0.w;
            u = d[r][eu+1]; v = d[r][ev+1]; d[r][eu+1] = u*M1.x + v*M1.z; d[r][ev+1] = u*M1.y + v*M1.w;
            u = d[r][eu+2]; v = d[r][ev+2]; d[r][eu+2] = u*M2.x + v*M2.z; d[r][ev+2] = u*M2.y + v*M2.w;
            u = d[r][eu+3]; v = d[r][ev+3]; d[r][eu+3] = u*M3.x + v*M3.z; d[r][ev+3] = u*M3.y + v*M3.w;
        }
    }

    // ---- store: coalesced float4, nontemporal (write-once stream) ----
    #pragma unroll
    for (int r = 0; r < RPW; ++r) {
        int row = row0 + r;
        if (row < rows) {
            f32x4* dst = (f32x4*)(out + (size_t)row * DIM);
            #pragma unroll
            for (int q = 0; q < 4; ++q) {
                f32x4 v;
                v.x = d[r][q*4+0]; v.y = d[r][q*4+1];
                v.z = d[r][q*4+2]; v.w = d[r][q*4+3];
                __builtin_nontemporal_store(v, &dst[q * 64 + lane]);
            }
        }
    }
}

extern "C" void kernel_launch(void* const* d_in, const int* in_sizes, int n_in,
                              void* d_out, int out_size, void* d_ws, size_t ws_size,
                              hipStream_t stream) {
    const float* x  = (const float*)d_in[0];
    const float* Ws = (const float*)d_in[1];
    float* out = (float*)d_out;

    int rows = in_sizes[0] / DIM;
    int grid = (rows + ROWS_PER_BLOCK - 1) / ROWS_PER_BLOCK;

    if (ws_size >= (size_t)PACKED_BYTES) {
        float* pw = (float*)d_ws;
        pack_weights<<<6, 256, 0, stream>>>(Ws, pw);
        butterfly_kernel<true><<<grid, 256, 0, stream>>>(x, Ws, pw, out, rows);
    } else {
        butterfly_kernel<false><<<grid, 256, 0, stream>>>(x, Ws, nullptr, out, rows);
    }
}